// Round 7
// baseline (32.731 us; speedup 1.0000x reference)
//
#include <hip/hip_runtime.h>
#include <math.h>

#define NUM_HEADS 16
#define DIM_HID 64
#define NUM_GAUSS 251
#define W_SCA_COLS 320   // DIM_HID + 256
#define GP 20            // padded stride (floats): 80B, 16B-aligned, banks spread 8-way
#define RAD 0.16f        // window radius: dropped terms < exp(-8)*|w| ~ 2e-5 each
#define TPB 256
#define EPB 512          // edges per block = 2 per thread

// ---------------------------------------------------------------------------
// 2-edges-per-thread kernel (r7). r5 skeleton (measured 24.0 us) + ILP:
// each thread owns TWO edges, all long-latency streams interleaved, so each
// wave carries 2 independent dependency chains (E/64=3125 waves is only
// 3/SIMD -- can't raise wave count, so widen the chains instead).
//
// Algebraic collapse (validated r2-r6, absmax 3.9e-3 vs 1.57e-2):
//   weff[h] = w_vec1[h,:] @ w_edge
//   vnorm block of out_sca = ||unit|| * A[o];  A = |weff| @ w_sca[:, :64]^T
//   out_vec[o,i] = B[o]*unit[i] -> output_vec = (sigmoid*B)^2 * ||unit||^2
// A,B folded per block (no d_ws cross-kernel state -- r1 lesson).
// Gauss: FIXED 9-iter unrolled window (coverage: ghi<=glo+8 provable).
// Etype: one-hot -> single LDS row. Gate: wave-uniform s_load weights.
// launch_bounds(256,4): VGPR<=128 (r6's (512,4) forced 64 -> spills).
// ---------------------------------------------------------------------------
__global__ __launch_bounds__(256, 4) void edge_kernel(
    const int* __restrict__ idxA,     // [E]
    const int* __restrict__ idxB,     // [E]
    const float* __restrict__ feat,   // [E,5]
    const float* __restrict__ pos,    // [N,3]
    const float* __restrict__ w_edge, // [64]
    const float* __restrict__ w_vec1, // [64,64]
    const float* __restrict__ w_vec2, // [16,64]
    const float* __restrict__ w_sca,  // [16,320]
    const float* __restrict__ w_gate, // [16,16]
    const float* __restrict__ b_gate, // [16]
    float* __restrict__ out,
    int E)
{
    __shared__ __align__(16) float wg[NUM_GAUSS * GP]; // gauss slice: row g = 16 heads
    __shared__ __align__(16) float wt5[5 * GP];        // etype rows (one-hot select)
    __shared__ __align__(16) float weff[64];
    __shared__ __align__(16) float As[16], Bs[16];

    const int tid = threadIdx.x;
    const int e0 = blockIdx.x * EPB + tid;
    const int e1 = e0 + TPB;
    const bool act0 = (e0 < E), act1 = (e1 < E);
    const int ec0 = act0 ? e0 : (E - 1);
    const int ec1 = act1 ? e1 : (E - 1);

    // --- early per-edge loads (latency hides under prologue) ---
    const int na0 = idxA[ec0], nb0 = idxB[ec0];
    const int na1 = idxA[ec1], nb1 = idxB[ec1];
    const float f01 = feat[ec0 * 5 + 1], f02 = feat[ec0 * 5 + 2];
    const float f03 = feat[ec0 * 5 + 3], f04 = feat[ec0 * 5 + 4];
    const float f11 = feat[ec1 * 5 + 1], f12 = feat[ec1 * 5 + 2];
    const float f13 = feat[ec1 * 5 + 3], f14 = feat[ec1 * 5 + 4];
    // pos gathers for both edges, issued together
    const float ax0 = pos[na0*3], ay0 = pos[na0*3+1], az0 = pos[na0*3+2];
    const float bx0 = pos[nb0*3], by0 = pos[nb0*3+1], bz0 = pos[nb0*3+2];
    const float ax1 = pos[na1*3], ay1 = pos[na1*3+1], az1 = pos[na1*3+2];
    const float bx1 = pos[nb1*3], by1 = pos[nb1*3+1], bz1 = pos[nb1*3+2];

    // --- stage gauss slice: 4016 / 256 ~ 16 iters ---
    for (int j = tid; j < 16 * NUM_GAUSS; j += TPB) {
        int o = j / NUM_GAUSS;          // magic-mul
        int g = j - o * NUM_GAUSS;
        wg[g * GP + o] = w_sca[o * W_SCA_COLS + DIM_HID + g];
    }
    if (tid < 80) {
        int t = tid >> 4, o = tid & 15;
        wt5[t * GP + o] = w_sca[o * W_SCA_COLS + DIM_HID + NUM_GAUSS + t];
    }
    // --- fold weff = w_vec1 @ w_edge ---
    if (tid < 64) {
        const float4* wrow = (const float4*)(w_vec1 + tid * 64);
        float s = 0.f;
        #pragma unroll
        for (int c4 = 0; c4 < 16; ++c4) {
            float4 v = wrow[c4];
            s += v.x * w_edge[c4*4+0] + v.y * w_edge[c4*4+1]
               + v.z * w_edge[c4*4+2] + v.w * w_edge[c4*4+3];
        }
        weff[tid] = s;
    }
    __syncthreads();
    if (tid < 16) {
        const float4* srow = (const float4*)(w_sca + tid * W_SCA_COLS);
        const float4* vrow = (const float4*)(w_vec2 + tid * 64);
        float a2 = 0.f, b2 = 0.f;
        #pragma unroll
        for (int k4 = 0; k4 < 16; ++k4) {
            float4 sv = srow[k4];
            float4 vv = vrow[k4];
            float4 wv = *(const float4*)&weff[k4 * 4];
            a2 += fabsf(wv.x)*sv.x + fabsf(wv.y)*sv.y + fabsf(wv.z)*sv.z + fabsf(wv.w)*sv.w;
            b2 += wv.x*vv.x + wv.y*vv.y + wv.z*vv.z + wv.w*vv.w;
        }
        As[tid] = a2;
        Bs[tid] = b2;
    }
    __syncthreads();

    // --- geometry, both edges ---
    const float vx0 = ax0-bx0, vy0 = ay0-by0, vz0 = az0-bz0;
    const float vx1 = ax1-bx1, vy1 = ay1-by1, vz1 = az1-bz1;
    const float d0 = sqrtf(vx0*vx0 + vy0*vy0 + vz0*vz0);
    const float d1 = sqrtf(vx1*vx1 + vy1*vy1 + vz1*vz1);
    const float un0 = d0 * __builtin_amdgcn_rcpf(d0 + 1e-7f);
    const float un1 = d1 * __builtin_amdgcn_rcpf(d1 + 1e-7f);
    const int ti0 = (int)(f01 + 2.f*f02 + 3.f*f03 + 4.f*f04 + 0.5f);
    const int ti1 = (int)(f11 + 2.f*f12 + 3.f*f13 + 4.f*f14 + 0.5f);

    // window base: fixed 9 rows starting at glo (coverage proven: ghi<=glo+8)
    int glo0 = (int)ceilf((d0 - RAD) * 25.f);
    int glo1 = (int)ceilf((d1 - RAD) * 25.f);
    glo0 = glo0 < 0 ? 0 : (glo0 > NUM_GAUSS-9 ? NUM_GAUSS-9 : glo0);
    glo1 = glo1 < 0 ? 0 : (glo1 > NUM_GAUSS-9 ? NUM_GAUSS-9 : glo1);
    const float x0 = d0 - (float)glo0 * 0.04f;
    const float x1 = d1 - (float)glo1 * 0.04f;

    // --- acc init: un*A + etype row (LDS) ---
    float acc0[16], acc1[16];
    {
        const float4* ar = (const float4*)As;
        const float4* t0r = (const float4*)&wt5[ti0 * GP];
        const float4* t1r = (const float4*)&wt5[ti1 * GP];
        #pragma unroll
        for (int q = 0; q < 4; ++q) {
            const float4 av = ar[q];
            const float4 tv0 = t0r[q];
            const float4 tv1 = t1r[q];
            acc0[4*q+0] = fmaf(un0, av.x, tv0.x); acc1[4*q+0] = fmaf(un1, av.x, tv1.x);
            acc0[4*q+1] = fmaf(un0, av.y, tv0.y); acc1[4*q+1] = fmaf(un1, av.y, tv1.y);
            acc0[4*q+2] = fmaf(un0, av.z, tv0.z); acc1[4*q+2] = fmaf(un1, av.z, tv1.z);
            acc0[4*q+3] = fmaf(un0, av.w, tv0.w); acc1[4*q+3] = fmaf(un1, av.w, tv1.w);
        }
    }

    // --- fixed-9 unrolled gauss, both edges interleaved ---
    {
        const float C2 = -312.5f * 1.44269504088896340736f;  // coeff * log2(e)
        const float* base0 = &wg[glo0 * GP];
        const float* base1 = &wg[glo1 * GP];
        #pragma unroll
        for (int i = 0; i < 9; ++i) {
            const float t0 = x0 - (float)i * 0.04f;
            const float t1 = x1 - (float)i * 0.04f;
            const float w0 = exp2f(C2 * t0 * t0);
            const float w1 = exp2f(C2 * t1 * t1);
            const float4* r0 = (const float4*)(base0 + i * GP);
            const float4* r1 = (const float4*)(base1 + i * GP);
            #pragma unroll
            for (int q = 0; q < 4; ++q) {
                const float4 v0 = r0[q];
                const float4 v1 = r1[q];
                acc0[4*q+0] += w0 * v0.x;  acc1[4*q+0] += w1 * v1.x;
                acc0[4*q+1] += w0 * v0.y;  acc1[4*q+1] += w1 * v1.y;
                acc0[4*q+2] += w0 * v0.z;  acc1[4*q+2] += w1 * v1.z;
                acc0[4*q+3] += w0 * v0.w;  acc1[4*q+3] += w1 * v1.w;
            }
        }
    }

    // --- store out_sca early ---
    if (act0) {
        float* o1 = out + (size_t)e0 * 16;
        #pragma unroll
        for (int o = 0; o < 16; o += 4)
            *(float4*)(o1 + o) = make_float4(acc0[o], acc0[o+1], acc0[o+2], acc0[o+3]);
    }
    if (act1) {
        float* o1 = out + (size_t)e1 * 16;
        #pragma unroll
        for (int o = 0; o < 16; o += 4)
            *(float4*)(o1 + o) = make_float4(acc1[o], acc1[o+1], acc1[o+2], acc1[o+3]);
    }

    // --- gates: wave-uniform s_load weights; both edges share each s_load ---
    const float NL2E = -1.44269504088896340736f;
    const float u20 = un0 * un0, u21 = un1 * un1;
    float* o20 = out + (size_t)E * 16 + (size_t)e0 * 16;
    float* o21 = out + (size_t)E * 16 + (size_t)e1 * 16;
    #pragma unroll
    for (int oq = 0; oq < 16; oq += 4) {
        float4 ov0, ov1;
        float* p0 = (float*)&ov0;
        float* p1 = (float*)&ov1;
        #pragma unroll
        for (int oi = 0; oi < 4; ++oi) {
            const int o = oq + oi;
            float x0g = b_gate[o], x1g = x0g;
            #pragma unroll
            for (int p = 0; p < 16; ++p) {
                const float wgt = w_gate[o * 16 + p];   // s_load, shared by both edges
                x0g = fmaf(acc0[p], wgt, x0g);
                x1g = fmaf(acc1[p], wgt, x1g);
            }
            const float g0 = __builtin_amdgcn_rcpf(1.0f + exp2f(NL2E * x0g));
            const float g1 = __builtin_amdgcn_rcpf(1.0f + exp2f(NL2E * x1g));
            const float bsv = Bs[o];
            const float gv0 = g0 * bsv, gv1 = g1 * bsv;
            p0[oi] = gv0 * gv0 * u20;
            p1[oi] = gv1 * gv1 * u21;
        }
        if (act0) *(float4*)(o20 + oq) = ov0;
        if (act1) *(float4*)(o21 + oq) = ov1;
    }
}

extern "C" void kernel_launch(void* const* d_in, const int* in_sizes, int n_in,
                              void* d_out, int out_size, void* d_ws, size_t ws_size,
                              hipStream_t stream) {
    const int*   idx    = (const int*)d_in[0];    // [2,E]
    const float* feat   = (const float*)d_in[1];  // [E,5]
    const float* pos    = (const float*)d_in[2];  // [N,3]
    const float* w_edge = (const float*)d_in[3];  // [64,1]
    const float* w_vec1 = (const float*)d_in[4];  // [64,64]
    const float* w_vec2 = (const float*)d_in[5];  // [16,64]
    const float* w_sca  = (const float*)d_in[6];  // [16,320]
    const float* w_gate = (const float*)d_in[7];  // [16,16]
    const float* b_gate = (const float*)d_in[8];  // [16]
    float* out = (float*)d_out;

    const int E = in_sizes[0] / 2;
    const int nblk = (E + EPB - 1) / EPB;
    edge_kernel<<<nblk, TPB, 0, stream>>>(idx, idx + E, feat, pos,
                                          w_edge, w_vec1, w_vec2,
                                          w_sca, w_gate, b_gate, out, E);
}

// Round 8
// 31.002 us; speedup vs baseline: 1.0558x; 1.0558x over previous
//
#include <hip/hip_runtime.h>
#include <math.h>

#define NUM_HEADS 16
#define DIM_HID 64
#define NUM_GAUSS 251
#define W_SCA_COLS 320   // DIM_HID + 256
#define GP 20            // padded stride (floats): 80B, 16B-aligned, banks spread 8-way
#define RAD 0.16f        // window radius: dropped terms < exp(-8)*|w| ~ 2e-5 each
#define TPB 512
#define EPB 128          // edges per block = TPB/4 (quad of lanes per edge)

// ---------------------------------------------------------------------------
// QUAD-PER-EDGE kernel (r8). r7's profile proved two structural limits:
//   (1) spills: VGPR=64 + 43MB phantom HBM traffic when per-thread arrays grow
//   (2) occupancy: 1 thr/edge = 3.05 waves/SIMD -> pure latency exposure
// Fix: 4 lanes per edge. 12.5K waves (8/SIMD resident), per-lane acc[4] only
// (no spill possible), quad lanes share gather addresses (HW merges).
//
// Algebraic collapse (validated r2-r7, absmax 3.9e-3 vs 1.57e-2):
//   weff[h] = w_vec1[h,:] @ w_edge
//   vnorm block of out_sca = ||unit|| * A[o];  A = |weff| @ w_sca[:, :64]^T
//   out_vec[o,i] = B[o]*unit[i] -> output_vec = (sigmoid*B)^2 * ||unit||^2
// Gauss: fixed-9 window (underflows to exact 0 outside). Etype one-hot row.
// Gate: full acc[16] via same-wave LDS round-trip (in-order DS, no barrier);
// weights via wave-uniform s_load; each lane keeps only its own 4 heads.
// ---------------------------------------------------------------------------
__global__ __launch_bounds__(TPB, 4) void edge_kernel(
    const int* __restrict__ idxA,     // [E]
    const int* __restrict__ idxB,     // [E]
    const float* __restrict__ feat,   // [E,5]
    const float* __restrict__ pos,    // [N,3]
    const float* __restrict__ w_edge, // [64]
    const float* __restrict__ w_vec1, // [64,64]
    const float* __restrict__ w_vec2, // [16,64]
    const float* __restrict__ w_sca,  // [16,320]
    const float* __restrict__ w_gate, // [16,16]
    const float* __restrict__ b_gate, // [16]
    float* __restrict__ out,
    int E)
{
    __shared__ __align__(16) float wg[NUM_GAUSS * GP]; // gauss slice: row g = 16 heads
    __shared__ __align__(16) float wt5[5 * GP];        // etype rows
    __shared__ __align__(16) float weff[64];
    __shared__ __align__(16) float As[16], Bs[16];
    __shared__ __align__(16) float sAcc[EPB * GP];     // per-edge acc exchange

    const int tid = threadIdx.x;
    const int q   = tid & 3;          // lane within quad
    const int h   = q << 2;           // own head base (0/4/8/12)
    const int el  = tid >> 2;         // edge slot in block (0..127)
    const int e   = blockIdx.x * EPB + el;
    const bool act = (e < E);
    const int ec  = act ? e : (E - 1);

    // --- early per-edge loads (quad lanes share addr -> HW merges) ---
    const int na = idxA[ec];
    const int nb = idxB[ec];
    const float f1 = feat[ec * 5 + 1], f2 = feat[ec * 5 + 2];
    const float f3 = feat[ec * 5 + 3], f4 = feat[ec * 5 + 4];

    // --- stage gauss slice: 4016 words / 512 thr ~ 8 iters ---
    for (int j = tid; j < 16 * NUM_GAUSS; j += TPB) {
        int o = j / NUM_GAUSS;          // magic-mul
        int g = j - o * NUM_GAUSS;
        wg[g * GP + o] = w_sca[o * W_SCA_COLS + DIM_HID + g];
    }
    if (tid < 80) {
        int t = tid >> 4, o = tid & 15;
        wt5[t * GP + o] = w_sca[o * W_SCA_COLS + DIM_HID + NUM_GAUSS + t];
    }
    // --- fold weff = w_vec1 @ w_edge ---
    if (tid < 64) {
        const float4* wrow = (const float4*)(w_vec1 + tid * 64);
        float s = 0.f;
        #pragma unroll
        for (int c4 = 0; c4 < 16; ++c4) {
            float4 v = wrow[c4];
            s += v.x * w_edge[c4*4+0] + v.y * w_edge[c4*4+1]
               + v.z * w_edge[c4*4+2] + v.w * w_edge[c4*4+3];
        }
        weff[tid] = s;
    }
    __syncthreads();
    if (tid < 16) {
        const float4* srow = (const float4*)(w_sca + tid * W_SCA_COLS);
        const float4* vrow = (const float4*)(w_vec2 + tid * 64);
        float a2 = 0.f, b2 = 0.f;
        #pragma unroll
        for (int k4 = 0; k4 < 16; ++k4) {
            float4 sv = srow[k4];
            float4 vv = vrow[k4];
            float4 wv = *(const float4*)&weff[k4 * 4];
            a2 += fabsf(wv.x)*sv.x + fabsf(wv.y)*sv.y + fabsf(wv.z)*sv.z + fabsf(wv.w)*sv.w;
            b2 += wv.x*vv.x + wv.y*vv.y + wv.z*vv.z + wv.w*vv.w;
        }
        As[tid] = a2;
        Bs[tid] = b2;
    }
    __syncthreads();

    // --- geometry (redundant across quad; same values) ---
    const float ax = pos[na*3+0], ay = pos[na*3+1], az = pos[na*3+2];
    const float bx = pos[nb*3+0], by = pos[nb*3+1], bz = pos[nb*3+2];
    const float vx = ax-bx, vy = ay-by, vz = az-bz;
    const float d  = sqrtf(vx*vx + vy*vy + vz*vz);
    const float un = d * __builtin_amdgcn_rcpf(d + 1e-7f);   // ||unit||
    const float u2 = un * un;
    const int ti = (int)(f1 + 2.f*f2 + 3.f*f3 + 4.f*f4 + 0.5f);

    int glo = (int)ceilf((d - RAD) * 25.f);
    glo = glo < 0 ? 0 : (glo > NUM_GAUSS - 9 ? NUM_GAUSS - 9 : glo);
    const float x0 = d - (float)glo * 0.04f;

    // --- acc[4] for own heads: un*A + etype ---
    const float4 av = *(const float4*)&As[h];
    const float4 tv = *(const float4*)&wt5[ti * GP + h];
    float a0 = fmaf(un, av.x, tv.x);
    float a1 = fmaf(un, av.y, tv.y);
    float a2 = fmaf(un, av.z, tv.z);
    float a3 = fmaf(un, av.w, tv.w);

    // --- fixed-9 gauss window: one ds_read_b128 per iter (own 4 heads) ---
    {
        const float C2 = -312.5f * 1.44269504088896340736f;  // coeff * log2(e)
        const float* base = &wg[glo * GP + h];
        #pragma unroll
        for (int i = 0; i < 9; ++i) {
            const float t = x0 - (float)i * 0.04f;
            const float w = exp2f(C2 * t * t);
            const float4 v = *(const float4*)(base + i * GP);
            a0 = fmaf(w, v.x, a0);
            a1 = fmaf(w, v.y, a1);
            a2 = fmaf(w, v.z, a2);
            a3 = fmaf(w, v.w, a3);
        }
    }

    // --- store out_sca (quad = 64B contiguous, wave = 1KB coalesced) ---
    if (act)
        *(float4*)(out + (size_t)e * 16 + h) = make_float4(a0, a1, a2, a3);

    // --- exchange acc across quad via LDS (same wave: DS in-order) ---
    *(float4*)&sAcc[el * GP + h] = make_float4(a0, a1, a2, a3);
    __builtin_amdgcn_wave_barrier();   // pin compiler ordering (HW is in-order)
    const float4 c0 = *(const float4*)&sAcc[el * GP + 0];
    const float4 c1 = *(const float4*)&sAcc[el * GP + 4];
    const float4 c2 = *(const float4*)&sAcc[el * GP + 8];
    const float4 c3 = *(const float4*)&sAcc[el * GP + 12];
    const float accv[16] = { c0.x,c0.y,c0.z,c0.w, c1.x,c1.y,c1.z,c1.w,
                             c2.x,c2.y,c2.z,c2.w, c3.x,c3.y,c3.z,c3.w };

    // --- gate: uniform s_load weights; keep own 4 pre-activations ---
    float xs0 = 0.f, xs1 = 0.f, xs2 = 0.f, xs3 = 0.f;
    #pragma unroll
    for (int o = 0; o < 16; ++o) {
        float x = b_gate[o];
        #pragma unroll
        for (int p = 0; p < 16; ++p) x = fmaf(accv[p], w_gate[o * 16 + p], x);
        const bool mine = (q == (o >> 2));
        if ((o & 3) == 0)      xs0 = mine ? x : xs0;
        else if ((o & 3) == 1) xs1 = mine ? x : xs1;
        else if ((o & 3) == 2) xs2 = mine ? x : xs2;
        else                   xs3 = mine ? x : xs3;
    }

    const float NL2E = -1.44269504088896340736f;
    const float4 bsv = *(const float4*)&Bs[h];
    const float g0 = __builtin_amdgcn_rcpf(1.0f + exp2f(NL2E * xs0));
    const float g1 = __builtin_amdgcn_rcpf(1.0f + exp2f(NL2E * xs1));
    const float g2 = __builtin_amdgcn_rcpf(1.0f + exp2f(NL2E * xs2));
    const float g3 = __builtin_amdgcn_rcpf(1.0f + exp2f(NL2E * xs3));
    const float v0 = g0 * bsv.x, v1 = g1 * bsv.y, v2 = g2 * bsv.z, v3 = g3 * bsv.w;

    if (act)
        *(float4*)(out + (size_t)E * 16 + (size_t)e * 16 + h) =
            make_float4(v0*v0*u2, v1*v1*u2, v2*v2*u2, v3*v3*u2);
}

extern "C" void kernel_launch(void* const* d_in, const int* in_sizes, int n_in,
                              void* d_out, int out_size, void* d_ws, size_t ws_size,
                              hipStream_t stream) {
    const int*   idx    = (const int*)d_in[0];    // [2,E]
    const float* feat   = (const float*)d_in[1];  // [E,5]
    const float* pos    = (const float*)d_in[2];  // [N,3]
    const float* w_edge = (const float*)d_in[3];  // [64,1]
    const float* w_vec1 = (const float*)d_in[4];  // [64,64]
    const float* w_vec2 = (const float*)d_in[5];  // [16,64]
    const float* w_sca  = (const float*)d_in[6];  // [16,320]
    const float* w_gate = (const float*)d_in[7];  // [16,16]
    const float* b_gate = (const float*)d_in[8];  // [16]
    float* out = (float*)d_out;

    const int E = in_sizes[0] / 2;
    const int nblk = (E + EPB - 1) / EPB;
    edge_kernel<<<nblk, TPB, 0, stream>>>(idx, idx + E, feat, pos,
                                          w_edge, w_vec1, w_vec2,
                                          w_sca, w_gate, b_gate, out, E);
}

// Round 9
// 24.393 us; speedup vs baseline: 1.3418x; 1.2709x over previous
//
#include <hip/hip_runtime.h>
#include <math.h>

#define NUM_HEADS 16
#define DIM_HID 64
#define NUM_GAUSS 251
#define W_SCA_COLS 320   // DIM_HID + 256
#define GP 20            // padded stride (floats): 80B, 16B-aligned
#define RAD 0.14f        // window radius: excluded terms < exp(-6.125)*|w| ~ 5e-4
#define NW 8             // fixed window iterations (span 2*RAD*25=7 -> 8 rows cover)
#define TPB 256
#define EPB 256

// ---------------------------------------------------------------------------
// r9: r5 skeleton (best measured, 24.0us) + TRANSACTION reduction.
// r7 profile showed effective mem throughput ~1.9 TB/s (24% of achievable):
// per-wave line-transactions ~1000 (scattered 16B stores = 512, divergent
// scalar gathers ~600) saturate the TA/L2 request path. Fixes:
//   - per-wave LDS transpose -> 4x contiguous 1KB wave-stores per array
//     (512 -> 64 store transactions/wave)
//   - pos as dwordx3 (6->2 instrs), feat f1..4 as one dwordx4 (4->1)
//   - RAD 0.14 -> fixed 8-iter window
// Occupancy theory is DEAD (r8: 8 waves/SIMD, no spills, still 31us).
// Algebraic collapse validated r2-r8 (absmax pinned at bf16 floor 3.9e-3):
//   weff = w_vec1 @ w_edge; out_sca = un*A + etype_row + gauss_window
//   output_vec = (sigmoid(out_sca@Wg^T+b)*B)^2 * un^2
// ---------------------------------------------------------------------------

struct F3 { float x, y, z; };

__global__ __launch_bounds__(TPB, 4) void edge_kernel(
    const int* __restrict__ idxA,     // [E]
    const int* __restrict__ idxB,     // [E]
    const float* __restrict__ feat,   // [E,5]
    const float* __restrict__ pos,    // [N,3]
    const float* __restrict__ w_edge, // [64]
    const float* __restrict__ w_vec1, // [64,64]
    const float* __restrict__ w_vec2, // [16,64]
    const float* __restrict__ w_sca,  // [16,320]
    const float* __restrict__ w_gate, // [16,16]
    const float* __restrict__ b_gate, // [16]
    float* __restrict__ out,
    int E)
{
    __shared__ __align__(16) float wg[NUM_GAUSS * GP]; // gauss slice: row g = 16 heads
    __shared__ __align__(16) float wt5[5 * GP];        // etype rows
    __shared__ __align__(16) float weff[64];
    __shared__ __align__(16) float As[16], Bs[16];
    __shared__ __align__(16) float sOut[4][64 * GP];   // per-wave transpose tile

    const int tid = threadIdx.x;
    const int e  = blockIdx.x * EPB + tid;
    const bool act = (e < E);
    const int ec = act ? e : (E - 1);

    // --- early per-edge loads, vectorized ---
    const int na = idxA[ec];
    const int nb = idxB[ec];
    float f14[4];
    __builtin_memcpy(f14, feat + ec * 5 + 1, 16);  // one dwordx4 (align 4)
    F3 pa3, pb3;                                    // dependent on idx
    __builtin_memcpy(&pa3, pos + na * 3, 12);       // dwordx3
    __builtin_memcpy(&pb3, pos + nb * 3, 12);

    // --- stage gauss slice: 4016 words / 256 thr ~ 16 iters ---
    for (int j = tid; j < 16 * NUM_GAUSS; j += TPB) {
        int o = j / NUM_GAUSS;          // magic-mul
        int g = j - o * NUM_GAUSS;
        wg[g * GP + o] = w_sca[o * W_SCA_COLS + DIM_HID + g];
    }
    if (tid < 80) {
        int t = tid >> 4, o = tid & 15;
        wt5[t * GP + o] = w_sca[o * W_SCA_COLS + DIM_HID + NUM_GAUSS + t];
    }
    // --- fold weff = w_vec1 @ w_edge ---
    if (tid < 64) {
        const float4* wrow = (const float4*)(w_vec1 + tid * 64);
        float s = 0.f;
        #pragma unroll
        for (int c4 = 0; c4 < 16; ++c4) {
            float4 v = wrow[c4];
            s += v.x * w_edge[c4*4+0] + v.y * w_edge[c4*4+1]
               + v.z * w_edge[c4*4+2] + v.w * w_edge[c4*4+3];
        }
        weff[tid] = s;
    }
    __syncthreads();
    if (tid < 16) {
        const float4* srow = (const float4*)(w_sca + tid * W_SCA_COLS);
        const float4* vrow = (const float4*)(w_vec2 + tid * 64);
        float a2 = 0.f, b2 = 0.f;
        #pragma unroll
        for (int k4 = 0; k4 < 16; ++k4) {
            float4 sv = srow[k4];
            float4 vv = vrow[k4];
            float4 wv = *(const float4*)&weff[k4 * 4];
            a2 += fabsf(wv.x)*sv.x + fabsf(wv.y)*sv.y + fabsf(wv.z)*sv.z + fabsf(wv.w)*sv.w;
            b2 += wv.x*vv.x + wv.y*vv.y + wv.z*vv.z + wv.w*vv.w;
        }
        As[tid] = a2;
        Bs[tid] = b2;
    }
    __syncthreads();

    // --- geometry ---
    const float vx = pa3.x - pb3.x, vy = pa3.y - pb3.y, vz = pa3.z - pb3.z;
    const float d  = sqrtf(vx*vx + vy*vy + vz*vz);
    const float un = d * __builtin_amdgcn_rcpf(d + 1e-7f);   // ||unit||
    const float u2 = un * un;
    const int ti = (int)(f14[0] + 2.f*f14[1] + 3.f*f14[2] + 4.f*f14[3] + 0.5f);

    int glo = (int)ceilf((d - RAD) * 25.f);
    glo = glo < 0 ? 0 : (glo > NUM_GAUSS - NW ? NUM_GAUSS - NW : glo);
    const float x0 = d - (float)glo * 0.04f;

    // --- acc init: un*A + etype row ---
    float acc[16];
    {
        const float4* ar  = (const float4*)As;
        const float4* t0r = (const float4*)&wt5[ti * GP];
        #pragma unroll
        for (int q = 0; q < 4; ++q) {
            const float4 av = ar[q];
            const float4 tv = t0r[q];
            acc[4*q+0] = fmaf(un, av.x, tv.x);
            acc[4*q+1] = fmaf(un, av.y, tv.y);
            acc[4*q+2] = fmaf(un, av.z, tv.z);
            acc[4*q+3] = fmaf(un, av.w, tv.w);
        }
    }

    // --- fixed-8 gauss window ---
    {
        const float C2 = -312.5f * 1.44269504088896340736f;  // coeff * log2(e)
        const float* base = &wg[glo * GP];
        #pragma unroll
        for (int i = 0; i < NW; ++i) {
            const float t = x0 - (float)i * 0.04f;
            const float w = exp2f(C2 * t * t);
            const float4* row = (const float4*)(base + i * GP);
            #pragma unroll
            for (int q = 0; q < 4; ++q) {
                const float4 v = row[q];
                acc[4*q+0] = fmaf(w, v.x, acc[4*q+0]);
                acc[4*q+1] = fmaf(w, v.y, acc[4*q+1]);
                acc[4*q+2] = fmaf(w, v.z, acc[4*q+2]);
                acc[4*q+3] = fmaf(w, v.w, acc[4*q+3]);
            }
        }
    }

    // --- transpose-store out_sca: per-wave LDS tile -> contiguous 1KB stores ---
    const int wv = tid >> 6, l = tid & 63;
    float* sw = sOut[wv];
    const int wbase = blockIdx.x * EPB + wv * 64;   // first edge of this wave
    #pragma unroll
    for (int q = 0; q < 4; ++q)
        *(float4*)&sw[l * GP + 4*q] = make_float4(acc[4*q], acc[4*q+1], acc[4*q+2], acc[4*q+3]);
    __builtin_amdgcn_wave_barrier();
    #pragma unroll
    for (int s = 0; s < 4; ++s) {
        const int r = s * 16 + (l >> 2);            // edge slot in wave
        const int c = (l & 3) * 4;                  // head quad
        const float4 v = *(const float4*)&sw[r * GP + c];
        if (wbase + r < E)
            *(float4*)(out + (size_t)(wbase + r) * 16 + c) = v;   // lane-contiguous
    }
    __builtin_amdgcn_wave_barrier();

    // --- gate: wave-uniform s_load weights ---
    const float NL2E = -1.44269504088896340736f;
    #pragma unroll
    for (int oq = 0; oq < 16; oq += 4) {
        float4 ov;
        float* po = (float*)&ov;
        #pragma unroll
        for (int oi = 0; oi < 4; ++oi) {
            const int o = oq + oi;
            float x = b_gate[o];
            #pragma unroll
            for (int p = 0; p < 16; ++p) x = fmaf(acc[p], w_gate[o * 16 + p], x);
            const float gate = __builtin_amdgcn_rcpf(1.0f + exp2f(NL2E * x));
            const float gv = gate * Bs[o];
            po[oi] = gv * gv * u2;
        }
        *(float4*)&sw[l * GP + oq] = ov;
    }
    __builtin_amdgcn_wave_barrier();
    float* outv = out + (size_t)E * 16;
    #pragma unroll
    for (int s = 0; s < 4; ++s) {
        const int r = s * 16 + (l >> 2);
        const int c = (l & 3) * 4;
        const float4 v = *(const float4*)&sw[r * GP + c];
        if (wbase + r < E)
            *(float4*)(outv + (size_t)(wbase + r) * 16 + c) = v;
    }
}

extern "C" void kernel_launch(void* const* d_in, const int* in_sizes, int n_in,
                              void* d_out, int out_size, void* d_ws, size_t ws_size,
                              hipStream_t stream) {
    const int*   idx    = (const int*)d_in[0];    // [2,E]
    const float* feat   = (const float*)d_in[1];  // [E,5]
    const float* pos    = (const float*)d_in[2];  // [N,3]
    const float* w_edge = (const float*)d_in[3];  // [64,1]
    const float* w_vec1 = (const float*)d_in[4];  // [64,64]
    const float* w_vec2 = (const float*)d_in[5];  // [16,64]
    const float* w_sca  = (const float*)d_in[6];  // [16,320]
    const float* w_gate = (const float*)d_in[7];  // [16,16]
    const float* b_gate = (const float*)d_in[8];  // [16]
    float* out = (float*)d_out;

    const int E = in_sizes[0] / 2;
    const int nblk = (E + EPB - 1) / EPB;
    edge_kernel<<<nblk, TPB, 0, stream>>>(idx, idx + E, feat, pos,
                                          w_edge, w_vec1, w_vec2,
                                          w_sca, w_gate, b_gate, out, E);
}

// Round 11
// 22.036 us; speedup vs baseline: 1.4854x; 1.1070x over previous
//
#include <hip/hip_runtime.h>
#include <math.h>

#define NUM_HEADS 16
#define DIM_HID 64
#define NUM_GAUSS 251
#define W_SCA_COLS 320   // DIM_HID + 256
#define GP 20            // padded stride (floats): 80B, 16B-aligned
#define RAD 0.14f        // window radius: excluded terms < exp(-6.125)*|w| ~ 5e-4
#define NW 8             // fixed window iterations
#define TPB 256
#define EPB 256

// native vector type for nontemporal builtins (HIP float4 is a class -> rejected)
typedef float f4 __attribute__((ext_vector_type(4)));

// ---------------------------------------------------------------------------
// r11 = r10 retry (compile fix only: ext_vector f4 for nontemporal stores).
// Theory: the 25.6MB write stream write-allocates in each XCD's 4MB L2 and
// continuously evicts the 600KB pos buffer; the 400K random pos gathers then
// miss to HBM (~900cy, 64B line refill each ~ 25MB random HBM traffic).
// Invariant across r3/r5/r8/r9 (all ~24us) -- matches the wall.
// Fix: output stores + single-use idx/feat non-temporal (bypass L2);
// pos stays cacheable -> L2-resident.
//
// Algebraic collapse validated r2-r9 (absmax pinned at 3.9e-3 vs 1.57e-2):
//   weff = w_vec1 @ w_edge;  A = |weff| @ w_sca[:,:64]^T;  B = w_vec2 @ weff
//   out_sca = un*A + etype_row + gauss_window(d)
//   output_vec = (sigmoid(out_sca@Wg^T + b) * B)^2 * un^2
// ---------------------------------------------------------------------------

struct F3 { float x, y, z; };

__global__ __launch_bounds__(TPB, 4) void edge_kernel(
    const int* __restrict__ idxA,     // [E]
    const int* __restrict__ idxB,     // [E]
    const float* __restrict__ feat,   // [E,5]
    const float* __restrict__ pos,    // [N,3]
    const float* __restrict__ w_edge, // [64]
    const float* __restrict__ w_vec1, // [64,64]
    const float* __restrict__ w_vec2, // [16,64]
    const float* __restrict__ w_sca,  // [16,320]
    const float* __restrict__ w_gate, // [16,16]
    const float* __restrict__ b_gate, // [16]
    float* __restrict__ out,
    int E)
{
    __shared__ __align__(16) float wg[NUM_GAUSS * GP]; // gauss slice: row g = 16 heads
    __shared__ __align__(16) float wt5[5 * GP];        // etype rows
    __shared__ __align__(16) float weff[64];
    __shared__ __align__(16) float As[16], Bs[16];
    __shared__ __align__(16) float sOut[4][64 * GP];   // per-wave transpose tile

    const int tid = threadIdx.x;
    const int e  = blockIdx.x * EPB + tid;
    const bool act = (e < E);
    const int ec = act ? e : (E - 1);

    // --- early per-edge loads; idx/feat single-use -> non-temporal ---
    const int na = __builtin_nontemporal_load(idxA + ec);
    const int nb = __builtin_nontemporal_load(idxB + ec);
    float f14[4];
    #pragma unroll
    for (int t = 0; t < 4; ++t)
        f14[t] = __builtin_nontemporal_load(feat + ec * 5 + 1 + t);
    F3 pa3, pb3;                                  // pos stays CACHEABLE (reused)
    __builtin_memcpy(&pa3, pos + na * 3, 12);     // dwordx3
    __builtin_memcpy(&pb3, pos + nb * 3, 12);

    // --- stage gauss slice: 4016 words / 256 thr ~ 16 iters ---
    for (int j = tid; j < 16 * NUM_GAUSS; j += TPB) {
        int o = j / NUM_GAUSS;          // magic-mul
        int g = j - o * NUM_GAUSS;
        wg[g * GP + o] = w_sca[o * W_SCA_COLS + DIM_HID + g];
    }
    if (tid < 80) {
        int t = tid >> 4, o = tid & 15;
        wt5[t * GP + o] = w_sca[o * W_SCA_COLS + DIM_HID + NUM_GAUSS + t];
    }
    // --- fold weff = w_vec1 @ w_edge ---
    if (tid < 64) {
        const float4* wrow = (const float4*)(w_vec1 + tid * 64);
        float s = 0.f;
        #pragma unroll
        for (int c4 = 0; c4 < 16; ++c4) {
            float4 v = wrow[c4];
            s += v.x * w_edge[c4*4+0] + v.y * w_edge[c4*4+1]
               + v.z * w_edge[c4*4+2] + v.w * w_edge[c4*4+3];
        }
        weff[tid] = s;
    }
    __syncthreads();
    if (tid < 16) {
        const float4* srow = (const float4*)(w_sca + tid * W_SCA_COLS);
        const float4* vrow = (const float4*)(w_vec2 + tid * 64);
        float a2 = 0.f, b2 = 0.f;
        #pragma unroll
        for (int k4 = 0; k4 < 16; ++k4) {
            float4 sv = srow[k4];
            float4 vv = vrow[k4];
            float4 wv = *(const float4*)&weff[k4 * 4];
            a2 += fabsf(wv.x)*sv.x + fabsf(wv.y)*sv.y + fabsf(wv.z)*sv.z + fabsf(wv.w)*sv.w;
            b2 += wv.x*vv.x + wv.y*vv.y + wv.z*vv.z + wv.w*vv.w;
        }
        As[tid] = a2;
        Bs[tid] = b2;
    }
    __syncthreads();

    // --- geometry ---
    const float vx = pa3.x - pb3.x, vy = pa3.y - pb3.y, vz = pa3.z - pb3.z;
    const float d  = sqrtf(vx*vx + vy*vy + vz*vz);
    const float un = d * __builtin_amdgcn_rcpf(d + 1e-7f);   // ||unit||
    const float u2 = un * un;
    const int ti = (int)(f14[0] + 2.f*f14[1] + 3.f*f14[2] + 4.f*f14[3] + 0.5f);

    int glo = (int)ceilf((d - RAD) * 25.f);
    glo = glo < 0 ? 0 : (glo > NUM_GAUSS - NW ? NUM_GAUSS - NW : glo);
    const float x0 = d - (float)glo * 0.04f;

    // --- acc init: un*A + etype row ---
    float acc[16];
    {
        const float4* ar  = (const float4*)As;
        const float4* t0r = (const float4*)&wt5[ti * GP];
        #pragma unroll
        for (int q = 0; q < 4; ++q) {
            const float4 av = ar[q];
            const float4 tv = t0r[q];
            acc[4*q+0] = fmaf(un, av.x, tv.x);
            acc[4*q+1] = fmaf(un, av.y, tv.y);
            acc[4*q+2] = fmaf(un, av.z, tv.z);
            acc[4*q+3] = fmaf(un, av.w, tv.w);
        }
    }

    // --- fixed-8 gauss window ---
    {
        const float C2 = -312.5f * 1.44269504088896340736f;  // coeff * log2(e)
        const float* base = &wg[glo * GP];
        #pragma unroll
        for (int i = 0; i < NW; ++i) {
            const float t = x0 - (float)i * 0.04f;
            const float w = exp2f(C2 * t * t);
            const float4* row = (const float4*)(base + i * GP);
            #pragma unroll
            for (int q = 0; q < 4; ++q) {
                const float4 v = row[q];
                acc[4*q+0] = fmaf(w, v.x, acc[4*q+0]);
                acc[4*q+1] = fmaf(w, v.y, acc[4*q+1]);
                acc[4*q+2] = fmaf(w, v.z, acc[4*q+2]);
                acc[4*q+3] = fmaf(w, v.w, acc[4*q+3]);
            }
        }
    }

    // --- transpose-store out_sca: LDS tile -> contiguous NON-TEMPORAL stores ---
    const int wv = tid >> 6, l = tid & 63;
    float* sw = sOut[wv];
    const int wbase = blockIdx.x * EPB + wv * 64;   // first edge of this wave
    #pragma unroll
    for (int q = 0; q < 4; ++q)
        *(float4*)&sw[l * GP + 4*q] = make_float4(acc[4*q], acc[4*q+1], acc[4*q+2], acc[4*q+3]);
    __builtin_amdgcn_wave_barrier();
    #pragma unroll
    for (int s = 0; s < 4; ++s) {
        const int r = s * 16 + (l >> 2);            // edge slot in wave
        const int c = (l & 3) * 4;                  // head quad
        const f4 v = *(const f4*)&sw[r * GP + c];
        if (wbase + r < E)
            __builtin_nontemporal_store(v, (f4*)(out + (size_t)(wbase + r) * 16 + c));
    }
    __builtin_amdgcn_wave_barrier();

    // --- gate: wave-uniform s_load weights ---
    const float NL2E = -1.44269504088896340736f;
    #pragma unroll
    for (int oq = 0; oq < 16; oq += 4) {
        float ov[4];
        #pragma unroll
        for (int oi = 0; oi < 4; ++oi) {
            const int o = oq + oi;
            float x = b_gate[o];
            #pragma unroll
            for (int p = 0; p < 16; ++p) x = fmaf(acc[p], w_gate[o * 16 + p], x);
            const float gate = __builtin_amdgcn_rcpf(1.0f + exp2f(NL2E * x));
            const float gv = gate * Bs[o];
            ov[oi] = gv * gv * u2;
        }
        *(float4*)&sw[l * GP + oq] = make_float4(ov[0], ov[1], ov[2], ov[3]);
    }
    __builtin_amdgcn_wave_barrier();
    float* outv = out + (size_t)E * 16;
    #pragma unroll
    for (int s = 0; s < 4; ++s) {
        const int r = s * 16 + (l >> 2);
        const int c = (l & 3) * 4;
        const f4 v = *(const f4*)&sw[r * GP + c];
        if (wbase + r < E)
            __builtin_nontemporal_store(v, (f4*)(outv + (size_t)(wbase + r) * 16 + c));
    }
}

extern "C" void kernel_launch(void* const* d_in, const int* in_sizes, int n_in,
                              void* d_out, int out_size, void* d_ws, size_t ws_size,
                              hipStream_t stream) {
    const int*   idx    = (const int*)d_in[0];    // [2,E]
    const float* feat   = (const float*)d_in[1];  // [E,5]
    const float* pos    = (const float*)d_in[2];  // [N,3]
    const float* w_edge = (const float*)d_in[3];  // [64,1]
    const float* w_vec1 = (const float*)d_in[4];  // [64,64]
    const float* w_vec2 = (const float*)d_in[5];  // [16,64]
    const float* w_sca  = (const float*)d_in[6];  // [16,320]
    const float* w_gate = (const float*)d_in[7];  // [16,16]
    const float* b_gate = (const float*)d_in[8];  // [16]
    float* out = (float*)d_out;

    const int E = in_sizes[0] / 2;
    const int nblk = (E + EPB - 1) / EPB;
    edge_kernel<<<nblk, TPB, 0, stream>>>(idx, idx + E, feat, pos,
                                          w_edge, w_vec1, w_vec2,
                                          w_sca, w_gate, b_gate, out, E);
}